// Round 7
// baseline (530.464 us; speedup 1.0000x reference)
//
#include <hip/hip_runtime.h>

#define DF 128
constexpr int N_NODES = 10000;
constexpr int N_EDGES = 640000;

typedef __bf16 bf16x8 __attribute__((ext_vector_type(8)));
typedef float f32x4 __attribute__((ext_vector_type(4)));
typedef __attribute__((address_space(3))) unsigned int lds_uint;
typedef const __attribute__((address_space(1))) unsigned int glb_uint;

// ---------- helpers ----------
__device__ __forceinline__ unsigned short f2bf(float f) {
  unsigned u = __builtin_bit_cast(unsigned, f);
  u += 0x7fffu + ((u >> 16) & 1u);   // RTNE
  return (unsigned short)(u >> 16);
}

__device__ __forceinline__ bf16x8 cvt8(float4 a, float4 b) {
  bf16x8 r;
  r[0] = (__bf16)a.x; r[1] = (__bf16)a.y; r[2] = (__bf16)a.z; r[3] = (__bf16)a.w;
  r[4] = (__bf16)b.x; r[5] = (__bf16)b.y; r[6] = (__bf16)b.z; r[7] = (__bf16)b.w;
  return r;
}

// stage a 16x128 C-layout tile (relu'd) into a 4KB LDS buffer, XOR-swizzled (HW-verified)
__device__ __forceinline__ void stage_h(char* bufj, const f32x4* accv, int grp, int row16) {
#pragma unroll
  for (int nt = 0; nt < 8; ++nt)
#pragma unroll
    for (int i = 0; i < 4; ++i) {
      const int r = grp * 4 + i;
      const int c = nt * 16 + row16;
      *(unsigned short*)(bufj + ((r * 256 + c * 2) ^ ((r & 7) << 4))) =
          f2bf(fmaxf(accv[nt][i], 0.f));
    }
}

// read an A-fragment (16 rows x 32 k) from a swizzled 4KB buffer (HW-verified)
__device__ __forceinline__ bf16x8 read_a(const char* bufj, int kt, int grp, int row16) {
  return *(const bf16x8*)(bufj + ((row16 * 256 + kt * 64 + grp * 16) ^ ((row16 & 7) << 4)));
}

// ---------- kernel 1: pack weights (verified K32 B-frag layout) + nodes->bf16 ----------
__global__ void pack_prep(const float* __restrict__ w0, const float* __restrict__ w1,
                          const float* __restrict__ w2, const float* __restrict__ nw0,
                          const float* __restrict__ nw1, const float* __restrict__ nw2,
                          const float* __restrict__ wn, const float* __restrict__ nodes,
                          unsigned short* __restrict__ dst, unsigned short* __restrict__ nbf) {
  int tid = blockIdx.x * blockDim.x + threadIdx.x;
  if (tid >= 163840 + N_NODES * DF) return;
  if (tid >= 163840) {                       // nodes -> bf16
    int p = tid - 163840;
    nbf[p] = f2bf(nodes[p]);
    return;
  }
  const float* src; int p;
  if (tid < 49152)       { src = w0;  p = tid; }
  else if (tid < 65536)  { src = w1;  p = tid - 49152; }
  else if (tid < 81920)  { src = w2;  p = tid - 65536; }
  else if (tid < 114688) { src = nw0; p = tid - 81920; }
  else if (tid < 131072) { src = nw1; p = tid - 114688; }
  else if (tid < 147456) { src = nw2; p = tid - 131072; }
  else                   { src = wn;  p = tid - 147456; }
  int i = p & 7, lane = (p >> 3) & 63, tile = p >> 9;
  int nt = tile & 7, kt = tile >> 3;
  int k = kt * 32 + ((lane >> 4) << 3) + i;
  int n = nt * 16 + (lane & 15);
  dst[tid] = f2bf(src[k * 128 + n]);
}

// ---------- CSR build ----------
__global__ void hist_kernel(const int* __restrict__ receivers, int* __restrict__ deg) {
  int e = blockIdx.x * blockDim.x + threadIdx.x;
  if (e < N_EDGES) atomicAdd(&deg[receivers[e]], 1);
}

__global__ void scan_kernel(const int* __restrict__ deg, int* __restrict__ rowstart) {
  __shared__ int part[1024];
  const int t = threadIdx.x;
  int loc[16];
  int s = 0;
#pragma unroll
  for (int j = 0; j < 16; ++j) {
    int idx = t * 16 + j;
    int v = (idx < N_NODES) ? deg[idx] : 0;
    loc[j] = s;
    s += v;
  }
  part[t] = s;
  __syncthreads();
  for (int off = 1; off < 1024; off <<= 1) {
    int v = part[t];
    int a = (t >= off) ? part[t - off] : 0;
    __syncthreads();
    part[t] = v + a;
    __syncthreads();
  }
  int base = (t > 0) ? part[t - 1] : 0;
#pragma unroll
  for (int j = 0; j < 16; ++j) {
    int idx = t * 16 + j;
    if (idx < N_NODES) rowstart[idx] = base + loc[j];
  }
  if (t == 0) rowstart[N_NODES] = part[1023];
}

__global__ void scatter_idx(const int* __restrict__ receivers, const int* __restrict__ senders,
                            const int* __restrict__ rowstart,
                            int* __restrict__ cursor, int* __restrict__ eid,
                            int* __restrict__ rid, int* __restrict__ ssend) {
  int e = blockIdx.x * blockDim.x + threadIdx.x;
  if (e >= N_EDGES) return;
  int r = receivers[e];
  int pos = atomicAdd(&cursor[r], 1);
  int q = rowstart[r] + pos;
  eid[q] = e;
  rid[q] = r;
  ssend[q] = senders[e];
}

// ---------- kernel 2: fused message MLP + register segmented-reduce scatter ----------
// 256 thr = 4 waves, 64 sorted positions/wave (4 subtiles of 16), grid 2500.
// Sender rows staged to per-wave LDS via global_load_lds (no dest VGPRs -> deep
// in-flight queue); sender tiles reused as h-transpose buffers after layer 0.
__global__ void __launch_bounds__(256, 2) msg_kernel(
    const float* __restrict__ edges,
    const int* __restrict__ eid, const int* __restrict__ rid, const int* __restrict__ ssend,
    const float* __restrict__ b0, const float* __restrict__ b1, const float* __restrict__ b2,
    const unsigned short* __restrict__ pw, const unsigned short* __restrict__ nbf,
    float* __restrict__ agg) {
  __shared__ char hs[65536];
  const int tid = threadIdx.x;
  const int lane = tid & 63, wave = tid >> 6;
  const int row16 = lane & 15, grp = lane >> 4;
  char* hb = hs + wave * 16384;
  const int pbase = blockIdx.x * 256 + wave * 64;

  int e_[4], rx[4];
#pragma unroll
  for (int s = 0; s < 4; ++s) {
    const int p = pbase + s * 16 + row16;
    e_[s] = eid[p];
    rx[s] = rid[p];
  }

  // ---- issue s0/s1 edge f32 loads (HBM stream) ----
  float4 t0[4][2], t1[4][2];
#pragma unroll
  for (int k2 = 0; k2 < 4; ++k2) {
    const float* p0 = edges + (size_t)e_[0] * DF + k2 * 32 + grp * 8;
    const float* p1 = edges + (size_t)e_[1] * DF + k2 * 32 + grp * 8;
    t0[k2][0] = *(const float4*)p0; t0[k2][1] = *(const float4*)(p0 + 4);
    t1[k2][0] = *(const float4*)p1; t1[k2][1] = *(const float4*)(p1 + 4);
  }

  // ---- stage sender rows into per-wave LDS tiles via global_load_lds ----
  // dest slot (r,c') in tile st holds source chunk c = c'^(r&7) of row ssend[..r]
  // (linear LDS dest, swizzled per-lane SOURCE -- rule-21-correct pairing)
#pragma unroll
  for (int st = 0; st < 4; ++st) {
#pragma unroll
    for (int j = 0; j < 4; ++j) {
      const int slot = j * 64 + lane;
      const int r = slot >> 4;        // 0..15 row within subtile
      const int cp = slot & 15;       // dest 16B-chunk
      const int sidx = ssend[pbase + st * 16 + r];
      const char* g = (const char*)nbf + (size_t)sidx * 256 + ((cp ^ (r & 7)) << 4);
      __builtin_amdgcn_global_load_lds((glb_uint*)g,
                                       (lds_uint*)(hb + st * 4096 + j * 1024), 16, 0, 0);
    }
  }

  // one drain for everything issued so far (~48 ops in flight)
  asm volatile("s_waitcnt vmcnt(0)" ::: "memory");
  __builtin_amdgcn_sched_barrier(0);

  // s0/s1 edges -> bf16 (frees 64 f32 regs); issue s2/s3 edge loads
  bf16x8 ebf[2][4];
#pragma unroll
  for (int k2 = 0; k2 < 4; ++k2) {
    ebf[0][k2] = cvt8(t0[k2][0], t0[k2][1]);
    ebf[1][k2] = cvt8(t1[k2][0], t1[k2][1]);
  }
  float4 ef[2][4][2];
#pragma unroll
  for (int s = 0; s < 2; ++s)
#pragma unroll
    for (int k2 = 0; k2 < 4; ++k2) {
      const float* p = edges + (size_t)e_[s + 2] * DF + k2 * 32 + grp * 8;
      ef[s][k2][0] = *(const float4*)p;
      ef[s][k2][1] = *(const float4*)(p + 4);
    }

  f32x4 acc[4][8];
#pragma unroll
  for (int nt = 0; nt < 8; ++nt) {
    float bv = b0[nt * 16 + row16];
#pragma unroll
    for (int s = 0; s < 4; ++s) acc[s][nt] = (f32x4){bv, bv, bv, bv};
  }

  // ---- layer 0, kc=0: sender A-frags from staged LDS (swizzled read) ----
#pragma unroll
  for (int k2 = 0; k2 < 4; ++k2) {
    bf16x8 af[4];
#pragma unroll
    for (int s = 0; s < 4; ++s)
      af[s] = *(const bf16x8*)(hb + s * 4096 + row16 * 256 +
                               ((((k2 << 2) + grp) ^ (row16 & 7)) << 4));
#pragma unroll
    for (int nt = 0; nt < 8; ++nt) {
      bf16x8 bw = *(const bf16x8*)(pw + ((size_t)(k2 * 8 + nt) * 64 + lane) * 8);
#pragma unroll
      for (int s = 0; s < 4; ++s)
        acc[s][nt] = __builtin_amdgcn_mfma_f32_16x16x32_bf16(af[s], bw, acc[s][nt], 0, 0, 0);
    }
  }

  // ---- layer 0, kc=1: receiver gathers (sorted -> L1-broadcast friendly) ----
#pragma unroll
  for (int k2 = 0; k2 < 4; ++k2) {
    bf16x8 af[4];
#pragma unroll
    for (int s = 0; s < 4; ++s)
      af[s] = *(const bf16x8*)(nbf + (size_t)rx[s] * DF + k2 * 32 + grp * 8);
#pragma unroll
    for (int nt = 0; nt < 8; ++nt) {
      bf16x8 bw = *(const bf16x8*)(pw + ((size_t)((4 + k2) * 8 + nt) * 64 + lane) * 8);
#pragma unroll
      for (int s = 0; s < 4; ++s)
        acc[s][nt] = __builtin_amdgcn_mfma_f32_16x16x32_bf16(af[s], bw, acc[s][nt], 0, 0, 0);
    }
  }

  // ---- layer 0, kc=2: edge features ----
#pragma unroll
  for (int k2 = 0; k2 < 4; ++k2) {
    bf16x8 af[4];
    af[0] = ebf[0][k2];
    af[1] = ebf[1][k2];
    af[2] = cvt8(ef[0][k2][0], ef[0][k2][1]);
    af[3] = cvt8(ef[1][k2][0], ef[1][k2][1]);
#pragma unroll
    for (int nt = 0; nt < 8; ++nt) {
      bf16x8 bw = *(const bf16x8*)(pw + ((size_t)((8 + k2) * 8 + nt) * 64 + lane) * 8);
#pragma unroll
      for (int s = 0; s < 4; ++s)
        acc[s][nt] = __builtin_amdgcn_mfma_f32_16x16x32_bf16(af[s], bw, acc[s][nt], 0, 0, 0);
    }
  }

  // ---- transpose h1 into the (now dead) sender tiles ----
#pragma unroll
  for (int s = 0; s < 4; ++s) stage_h(hb + s * 4096, acc[s], grp, row16);
  asm volatile("s_waitcnt lgkmcnt(0)" ::: "memory");
  __builtin_amdgcn_sched_barrier(0);

  // ---- layer 1 ----
  f32x4 acc2[4][8];
#pragma unroll
  for (int nt = 0; nt < 8; ++nt) {
    float bv = b1[nt * 16 + row16];
#pragma unroll
    for (int s = 0; s < 4; ++s) acc2[s][nt] = (f32x4){bv, bv, bv, bv};
  }
  const unsigned short* w1p = pw + 49152;
#pragma unroll
  for (int kt = 0; kt < 4; ++kt) {
    bf16x8 af[4];
#pragma unroll
    for (int s = 0; s < 4; ++s) af[s] = read_a(hb + s * 4096, kt, grp, row16);
#pragma unroll
    for (int nt = 0; nt < 8; ++nt) {
      bf16x8 bw = *(const bf16x8*)(w1p + ((size_t)(kt * 8 + nt) * 64 + lane) * 8);
#pragma unroll
      for (int s = 0; s < 4; ++s)
        acc2[s][nt] = __builtin_amdgcn_mfma_f32_16x16x32_bf16(af[s], bw, acc2[s][nt], 0, 0, 0);
    }
  }
  asm volatile("s_waitcnt lgkmcnt(0)" ::: "memory");
  __builtin_amdgcn_sched_barrier(0);

#pragma unroll
  for (int s = 0; s < 4; ++s) stage_h(hb + s * 4096, acc2[s], grp, row16);
  asm volatile("s_waitcnt lgkmcnt(0)" ::: "memory");
  __builtin_amdgcn_sched_barrier(0);

  // ---- layer 2 (no relu) ----
  f32x4 acc3[4][8];
#pragma unroll
  for (int nt = 0; nt < 8; ++nt) {
    float bv = b2[nt * 16 + row16];
#pragma unroll
    for (int s = 0; s < 4; ++s) acc3[s][nt] = (f32x4){bv, bv, bv, bv};
  }
  const unsigned short* w2p = pw + 65536;
#pragma unroll
  for (int kt = 0; kt < 4; ++kt) {
    bf16x8 af[4];
#pragma unroll
    for (int s = 0; s < 4; ++s) af[s] = read_a(hb + s * 4096, kt, grp, row16);
#pragma unroll
    for (int nt = 0; nt < 8; ++nt) {
      bf16x8 bw = *(const bf16x8*)(w2p + ((size_t)(kt * 8 + nt) * 64 + lane) * 8);
#pragma unroll
      for (int s = 0; s < 4; ++s)
        acc3[s][nt] = __builtin_amdgcn_mfma_f32_16x16x32_bf16(af[s], bw, acc3[s][nt], 0, 0, 0);
    }
  }

  // ---- epilogue: register segmented reduction over sorted receiver runs ----
#pragma unroll
  for (int s = 0; s < 4; ++s) {
    const int q = pbase + s * 16 + grp * 4;
    const int ru = rid[pbase + s * 16];                 // wave-uniform
    const bool uni = (ru == rid[pbase + s * 16 + 15]);  // whole subtile one receiver
    if (uni) {
#pragma unroll
      for (int nt = 0; nt < 8; ++nt) {
        float t = acc3[s][nt][0] + acc3[s][nt][1] + acc3[s][nt][2] + acc3[s][nt][3];
        t += __shfl_xor(t, 16);
        t += __shfl_xor(t, 32);
        if (grp == 0)
          unsafeAtomicAdd(agg + (size_t)ru * DF + nt * 16 + row16, t);
      }
    } else {
      const int ra = rid[q], rb = rid[q + 1], rc = rid[q + 2], rd = rid[q + 3];
#pragma unroll
      for (int nt = 0; nt < 8; ++nt) {
        const int col = nt * 16 + row16;
        float run = acc3[s][nt][0];
        if (rb != ra) { unsafeAtomicAdd(agg + (size_t)ra * DF + col, run); run = 0.f; }
        run += acc3[s][nt][1];
        if (rc != rb) { unsafeAtomicAdd(agg + (size_t)rb * DF + col, run); run = 0.f; }
        run += acc3[s][nt][2];
        if (rd != rc) { unsafeAtomicAdd(agg + (size_t)rc * DF + col, run); run = 0.f; }
        run += acc3[s][nt][3];
        unsafeAtomicAdd(agg + (size_t)rd * DF + col, run);
      }
    }
  }
}

// ---------- kernel 3: node MLP + residual + LayerNorm (verified, unchanged) ----------
__global__ void __launch_bounds__(256) node_kernel(
    const float* __restrict__ nodes, const float* __restrict__ agg,
    const float* __restrict__ nb0, const float* __restrict__ nb1, const float* __restrict__ nb2,
    const unsigned short* __restrict__ pnw0, const unsigned short* __restrict__ pnw1,
    const unsigned short* __restrict__ pnw2, const unsigned short* __restrict__ pwn,
    const float* __restrict__ ln_s, const float* __restrict__ ln_b,
    float* __restrict__ out) {
  __shared__ char hs[16384];
  const int tid = threadIdx.x, lane = tid & 63, wave = tid >> 6;
  const int row16 = lane & 15, grp = lane >> 4;
  char* hb = hs + wave * 4096;
  const int rb = blockIdx.x * 64 + wave * 16;
  const int rA = min(rb + row16, N_NODES - 1);

  f32x4 acc[8];
#pragma unroll
  for (int nt = 0; nt < 8; ++nt) {
    float b = nb0[nt * 16 + row16];
    acc[nt] = (f32x4){b, b, b, b};
  }
#pragma unroll
  for (int kt = 0; kt < 8; ++kt) {
    const float* p = (kt < 4) ? (nodes + (size_t)rA * DF + kt * 32)
                              : (agg + (size_t)rA * DF + (kt - 4) * 32);
    p += grp * 8;
    float4 f0 = *(const float4*)p, f1 = *(const float4*)(p + 4);
    bf16x8 af = cvt8(f0, f1);
#pragma unroll
    for (int nt = 0; nt < 8; ++nt) {
      bf16x8 bw = *(const bf16x8*)(pnw0 + ((size_t)(kt * 8 + nt) * 64 + lane) * 8);
      acc[nt] = __builtin_amdgcn_mfma_f32_16x16x32_bf16(af, bw, acc[nt], 0, 0, 0);
    }
  }
  stage_h(hb, acc, grp, row16);
  asm volatile("s_waitcnt lgkmcnt(0)" ::: "memory");
  __builtin_amdgcn_sched_barrier(0);

  f32x4 acc2[8];
#pragma unroll
  for (int nt = 0; nt < 8; ++nt) {
    float b = nb1[nt * 16 + row16];
    acc2[nt] = (f32x4){b, b, b, b};
  }
#pragma unroll
  for (int kt = 0; kt < 4; ++kt) {
    bf16x8 af = read_a(hb, kt, grp, row16);
#pragma unroll
    for (int nt = 0; nt < 8; ++nt) {
      bf16x8 bw = *(const bf16x8*)(pnw1 + ((size_t)(kt * 8 + nt) * 64 + lane) * 8);
      acc2[nt] = __builtin_amdgcn_mfma_f32_16x16x32_bf16(af, bw, acc2[nt], 0, 0, 0);
    }
  }
  asm volatile("s_waitcnt lgkmcnt(0)" ::: "memory");
  __builtin_amdgcn_sched_barrier(0);
  stage_h(hb, acc2, grp, row16);
  asm volatile("s_waitcnt lgkmcnt(0)" ::: "memory");
  __builtin_amdgcn_sched_barrier(0);

  f32x4 acc3[8];
#pragma unroll
  for (int nt = 0; nt < 8; ++nt) {
    float b = nb2[nt * 16 + row16];
    acc3[nt] = (f32x4){b, b, b, b};
  }
#pragma unroll
  for (int kt = 0; kt < 4; ++kt) {
    bf16x8 af = read_a(hb, kt, grp, row16);
#pragma unroll
    for (int nt = 0; nt < 8; ++nt) {
      bf16x8 bw = *(const bf16x8*)(pnw2 + ((size_t)(kt * 8 + nt) * 64 + lane) * 8);
      acc3[nt] = __builtin_amdgcn_mfma_f32_16x16x32_bf16(af, bw, acc3[nt], 0, 0, 0);
    }
  }
  f32x4 accR[8];
#pragma unroll
  for (int nt = 0; nt < 8; ++nt) accR[nt] = (f32x4){0.f, 0.f, 0.f, 0.f};
#pragma unroll
  for (int kt = 0; kt < 4; ++kt) {
    const float* p = nodes + (size_t)rA * DF + kt * 32 + grp * 8;
    float4 f0 = *(const float4*)p, f1 = *(const float4*)(p + 4);
    bf16x8 af = cvt8(f0, f1);
#pragma unroll
    for (int nt = 0; nt < 8; ++nt) {
      bf16x8 bw = *(const bf16x8*)(pwn + ((size_t)(kt * 8 + nt) * 64 + lane) * 8);
      accR[nt] = __builtin_amdgcn_mfma_f32_16x16x32_bf16(af, bw, accR[nt], 0, 0, 0);
    }
  }

  float y[8][4];
#pragma unroll
  for (int nt = 0; nt < 8; ++nt)
#pragma unroll
    for (int i = 0; i < 4; ++i) y[nt][i] = acc3[nt][i] + accR[nt][i];

  float mean[4], rstd[4];
#pragma unroll
  for (int i = 0; i < 4; ++i) {
    float s = 0.f;
#pragma unroll
    for (int nt = 0; nt < 8; ++nt) s += y[nt][i];
    s += __shfl_xor(s, 1); s += __shfl_xor(s, 2);
    s += __shfl_xor(s, 4); s += __shfl_xor(s, 8);
    mean[i] = s * (1.0f / 128.0f);
  }
#pragma unroll
  for (int i = 0; i < 4; ++i) {
    float v = 0.f;
#pragma unroll
    for (int nt = 0; nt < 8; ++nt) {
      float d = y[nt][i] - mean[i];
      v += d * d;
    }
    v += __shfl_xor(v, 1); v += __shfl_xor(v, 2);
    v += __shfl_xor(v, 4); v += __shfl_xor(v, 8);
    rstd[i] = rsqrtf(v * (1.0f / 128.0f) + 1e-6f);
  }
#pragma unroll
  for (int nt = 0; nt < 8; ++nt) {
    const float ls = ln_s[nt * 16 + row16];
    const float lb = ln_b[nt * 16 + row16];
#pragma unroll
    for (int i = 0; i < 4; ++i) {
      const int r = rb + grp * 4 + i;
      if (r < N_NODES)
        out[(size_t)r * DF + nt * 16 + row16] = (y[nt][i] - mean[i]) * rstd[i] * ls + lb;
    }
  }
}

// ---------- launch ----------
extern "C" void kernel_launch(void* const* d_in, const int* in_sizes, int n_in,
                              void* d_out, int out_size, void* d_ws, size_t ws_size,
                              hipStream_t stream) {
  const float* nodes     = (const float*)d_in[0];
  const float* edges     = (const float*)d_in[1];
  const int*   senders   = (const int*)d_in[2];
  const int*   receivers = (const int*)d_in[3];
  const float* msg_w0 = (const float*)d_in[4];
  const float* msg_b0 = (const float*)d_in[5];
  const float* msg_w1 = (const float*)d_in[6];
  const float* msg_b1 = (const float*)d_in[7];
  const float* msg_w2 = (const float*)d_in[8];
  const float* msg_b2 = (const float*)d_in[9];
  const float* node_w0 = (const float*)d_in[10];
  const float* node_b0 = (const float*)d_in[11];
  const float* node_w1 = (const float*)d_in[12];
  const float* node_b1 = (const float*)d_in[13];
  const float* node_w2 = (const float*)d_in[14];
  const float* node_b2 = (const float*)d_in[15];
  const float* w_node   = (const float*)d_in[16];
  const float* ln_scale = (const float*)d_in[17];
  const float* ln_bias  = (const float*)d_in[18];

  char* ws = (char*)d_ws;
  float* agg            = (float*)ws;                          // 5,120,000 B
  unsigned short* pw    = (unsigned short*)(ws + 5120000);     //   327,680 B
  unsigned short* nbf   = (unsigned short*)(ws + 5447680);     // 2,560,000 B
  int* deg              = (int*)(ws + 8007680);                //    40,000 B
  int* cursor           = (int*)(ws + 8047680);                //    40,000 B
  int* rowstart         = (int*)(ws + 8087680);                //    40,008 B
  int* eid              = (int*)(ws + 8127688);                // 2,560,000 B
  int* rid              = (int*)(ws + 10687688);               // 2,560,000 B
  int* ssend            = (int*)(ws + 13247688);               // 2,560,000 B (end ~15.8 MB)

  hipMemsetAsync(agg, 0, (size_t)N_NODES * DF * sizeof(float), stream);
  hipMemsetAsync(deg, 0, 80000, stream);   // deg + cursor (adjacent)

  pack_prep<<<(163840 + N_NODES * DF) / 256, 256, 0, stream>>>(
      msg_w0, msg_w1, msg_w2, node_w0, node_w1, node_w2, w_node, nodes, pw, nbf);

  hist_kernel<<<N_EDGES / 256, 256, 0, stream>>>(receivers, deg);
  scan_kernel<<<1, 1024, 0, stream>>>(deg, rowstart);
  scatter_idx<<<N_EDGES / 256, 256, 0, stream>>>(receivers, senders, rowstart, cursor,
                                                 eid, rid, ssend);

  msg_kernel<<<N_EDGES / 256, 256, 0, stream>>>(
      edges, eid, rid, ssend, msg_b0, msg_b1, msg_b2, pw, nbf, agg);

  node_kernel<<<157, 256, 0, stream>>>(nodes, agg, node_b0, node_b1, node_b2,
                                       pw + 81920, pw + 114688, pw + 131072, pw + 147456,
                                       ln_scale, ln_bias, (float*)d_out);
}

// Round 8
// 380.915 us; speedup vs baseline: 1.3926x; 1.3926x over previous
//
#include <hip/hip_runtime.h>

#define DF 128
constexpr int N_NODES = 10000;
constexpr int N_EDGES = 640000;

typedef __bf16 bf16x8 __attribute__((ext_vector_type(8)));
typedef float f32x4 __attribute__((ext_vector_type(4)));

// ---------- helpers ----------
__device__ __forceinline__ unsigned short f2bf(float f) {
  unsigned u = __builtin_bit_cast(unsigned, f);
  u += 0x7fffu + ((u >> 16) & 1u);   // RTNE
  return (unsigned short)(u >> 16);
}

__device__ __forceinline__ bf16x8 cvt8(float4 a, float4 b) {
  bf16x8 r;
  r[0] = (__bf16)a.x; r[1] = (__bf16)a.y; r[2] = (__bf16)a.z; r[3] = (__bf16)a.w;
  r[4] = (__bf16)b.x; r[5] = (__bf16)b.y; r[6] = (__bf16)b.z; r[7] = (__bf16)b.w;
  return r;
}

// stage a 16x128 C-layout tile into a 4KB LDS buffer, XOR-swizzled (HW-verified addresses)
template <bool RELU>
__device__ __forceinline__ void stage_t(char* bufj, const f32x4* accv, int grp, int row16) {
#pragma unroll
  for (int nt = 0; nt < 8; ++nt)
#pragma unroll
    for (int i = 0; i < 4; ++i) {
      const int r = grp * 4 + i;
      const int c = nt * 16 + row16;
      float v = RELU ? fmaxf(accv[nt][i], 0.f) : accv[nt][i];
      *(unsigned short*)(bufj + ((r * 256 + c * 2) ^ ((r & 7) << 4))) = f2bf(v);
    }
}

// read an A-fragment (16 rows x 32 k) from a swizzled 4KB buffer (HW-verified)
__device__ __forceinline__ bf16x8 read_a(const char* bufj, int kt, int grp, int row16) {
  return *(const bf16x8*)(bufj + ((row16 * 256 + kt * 64 + grp * 16) ^ ((row16 & 7) << 4)));
}

// ---------- kernel 1: pack weights (verified K32 B-frag layout) + nodes->bf16 ----------
__global__ void pack_prep(const float* __restrict__ w0, const float* __restrict__ w1,
                          const float* __restrict__ w2, const float* __restrict__ nw0,
                          const float* __restrict__ nw1, const float* __restrict__ nw2,
                          const float* __restrict__ wn, const float* __restrict__ nodes,
                          unsigned short* __restrict__ dst, unsigned short* __restrict__ nbf) {
  int tid = blockIdx.x * blockDim.x + threadIdx.x;
  if (tid >= 163840 + N_NODES * DF) return;
  if (tid >= 163840) {                       // nodes -> bf16
    int p = tid - 163840;
    nbf[p] = f2bf(nodes[p]);
    return;
  }
  const float* src; int p;
  if (tid < 49152)       { src = w0;  p = tid; }
  else if (tid < 65536)  { src = w1;  p = tid - 49152; }
  else if (tid < 81920)  { src = w2;  p = tid - 65536; }
  else if (tid < 114688) { src = nw0; p = tid - 81920; }
  else if (tid < 131072) { src = nw1; p = tid - 114688; }
  else if (tid < 147456) { src = nw2; p = tid - 131072; }
  else                   { src = wn;  p = tid - 147456; }
  int i = p & 7, lane = (p >> 3) & 63, tile = p >> 9;
  int nt = tile & 7, kt = tile >> 3;
  int k = kt * 32 + ((lane >> 4) << 3) + i;
  int n = nt * 16 + (lane & 15);
  dst[tid] = f2bf(src[k * 128 + n]);
}

// ---------- CSR build ----------
__global__ void hist_kernel(const int* __restrict__ receivers, int* __restrict__ deg) {
  int e = blockIdx.x * blockDim.x + threadIdx.x;
  if (e < N_EDGES) atomicAdd(&deg[receivers[e]], 1);
}

__global__ void scan_kernel(const int* __restrict__ deg, int* __restrict__ rowstart) {
  __shared__ int part[1024];
  const int t = threadIdx.x;
  int loc[16];
  int s = 0;
#pragma unroll
  for (int j = 0; j < 16; ++j) {
    int idx = t * 16 + j;
    int v = (idx < N_NODES) ? deg[idx] : 0;
    loc[j] = s;
    s += v;
  }
  part[t] = s;
  __syncthreads();
  for (int off = 1; off < 1024; off <<= 1) {
    int v = part[t];
    int a = (t >= off) ? part[t - off] : 0;
    __syncthreads();
    part[t] = v + a;
    __syncthreads();
  }
  int base = (t > 0) ? part[t - 1] : 0;
#pragma unroll
  for (int j = 0; j < 16; ++j) {
    int idx = t * 16 + j;
    if (idx < N_NODES) rowstart[idx] = base + loc[j];
  }
  if (t == 0) rowstart[N_NODES] = part[1023];
}

__global__ void scatter_idx(const int* __restrict__ receivers, const int* __restrict__ senders,
                            const int* __restrict__ rowstart,
                            int* __restrict__ cursor, int* __restrict__ eid,
                            int* __restrict__ rid, int* __restrict__ ssend) {
  int e = blockIdx.x * blockDim.x + threadIdx.x;
  if (e >= N_EDGES) return;
  int r = receivers[e];
  int pos = atomicAdd(&cursor[r], 1);
  int q = rowstart[r] + pos;
  eid[q] = e;
  rid[q] = r;
  ssend[q] = senders[e];
}

// ---------- kernel 2: P = nodes@W0a, Q = nodes@W0b (f32 out) ----------
__global__ void __launch_bounds__(256) pq_kernel(
    const unsigned short* __restrict__ nbf, const unsigned short* __restrict__ pw,
    float* __restrict__ P, float* __restrict__ Q) {
  const int tid = threadIdx.x, lane = tid & 63, wave = tid >> 6;
  const int row16 = lane & 15, grp = lane >> 4;
  const int rb = blockIdx.x * 64 + wave * 16;
  const int rA = min(rb + row16, N_NODES - 1);

  f32x4 aP[8], aQ[8];
#pragma unroll
  for (int nt = 0; nt < 8; ++nt) {
    aP[nt] = (f32x4){0.f, 0.f, 0.f, 0.f};
    aQ[nt] = (f32x4){0.f, 0.f, 0.f, 0.f};
  }
#pragma unroll
  for (int kt = 0; kt < 4; ++kt) {
    bf16x8 af = *(const bf16x8*)(nbf + (size_t)rA * DF + kt * 32 + grp * 8);
#pragma unroll
    for (int nt = 0; nt < 8; ++nt) {
      bf16x8 bwP = *(const bf16x8*)(pw + ((size_t)(kt * 8 + nt) * 64 + lane) * 8);
      bf16x8 bwQ = *(const bf16x8*)(pw + ((size_t)((4 + kt) * 8 + nt) * 64 + lane) * 8);
      aP[nt] = __builtin_amdgcn_mfma_f32_16x16x32_bf16(af, bwP, aP[nt], 0, 0, 0);
      aQ[nt] = __builtin_amdgcn_mfma_f32_16x16x32_bf16(af, bwQ, aQ[nt], 0, 0, 0);
    }
  }
#pragma unroll
  for (int nt = 0; nt < 8; ++nt)
#pragma unroll
    for (int i = 0; i < 4; ++i) {
      const int r = rb + grp * 4 + i;
      if (r < N_NODES) {
        P[(size_t)r * DF + nt * 16 + row16] = aP[nt][i];
        Q[(size_t)r * DF + nt * 16 + row16] = aQ[nt][i];
      }
    }
}

// ---------- kernel 3: edge MLP through h2 + scatter-add of h2 ----------
// h1 = relu(E@W0c + b0 + P[s] + Q[r]); h2 = relu(h1@W1 + b1); hsum += h2 per receiver.
// 256 thr = 4 waves, 64 sorted positions/wave (4 subtiles of 16), grid 2500.
__global__ void __launch_bounds__(256, 2) msg_kernel(
    const float* __restrict__ edges,
    const int* __restrict__ eid, const int* __restrict__ rid, const int* __restrict__ ssend,
    const float* __restrict__ b0, const float* __restrict__ b1,
    const unsigned short* __restrict__ pw,
    const float* __restrict__ P, const float* __restrict__ Q,
    float* __restrict__ hsum) {
  __shared__ char hs[65536];
  const int tid = threadIdx.x;
  const int lane = tid & 63, wave = tid >> 6;
  const int row16 = lane & 15, grp = lane >> 4;
  char* hb = hs + wave * 16384;
  const int pbase = blockIdx.x * 256 + wave * 64;

  int e_[4], rx[4], sx[4];
#pragma unroll
  for (int s = 0; s < 4; ++s) {
    const int p = pbase + s * 16 + row16;
    e_[s] = eid[p];
    rx[s] = rid[p];
    sx[s] = ssend[p];
  }

  // ---- edge rows: s0/s1 then s2/s3 (HBM stream) ----
  bf16x8 ebf[4][4];
  {
    float4 t0[4][2], t1[4][2];
#pragma unroll
    for (int k2 = 0; k2 < 4; ++k2) {
      const float* p0 = edges + (size_t)e_[0] * DF + k2 * 32 + grp * 8;
      const float* p1 = edges + (size_t)e_[1] * DF + k2 * 32 + grp * 8;
      t0[k2][0] = *(const float4*)p0; t0[k2][1] = *(const float4*)(p0 + 4);
      t1[k2][0] = *(const float4*)p1; t1[k2][1] = *(const float4*)(p1 + 4);
    }
#pragma unroll
    for (int k2 = 0; k2 < 4; ++k2) {
      ebf[0][k2] = cvt8(t0[k2][0], t0[k2][1]);
      ebf[1][k2] = cvt8(t1[k2][0], t1[k2][1]);
    }
#pragma unroll
    for (int k2 = 0; k2 < 4; ++k2) {
      const float* p2 = edges + (size_t)e_[2] * DF + k2 * 32 + grp * 8;
      const float* p3 = edges + (size_t)e_[3] * DF + k2 * 32 + grp * 8;
      t0[k2][0] = *(const float4*)p2; t0[k2][1] = *(const float4*)(p2 + 4);
      t1[k2][0] = *(const float4*)p3; t1[k2][1] = *(const float4*)(p3 + 4);
    }
#pragma unroll
    for (int k2 = 0; k2 < 4; ++k2) {
      ebf[2][k2] = cvt8(t0[k2][0], t0[k2][1]);
      ebf[3][k2] = cvt8(t1[k2][0], t1[k2][1]);
    }
  }

  // ---- layer 0 (edge part only): K=128 with W0c = rows 256..383 of W0 ----
  f32x4 acc[4][8];
#pragma unroll
  for (int nt = 0; nt < 8; ++nt) {
    float bv = b0[nt * 16 + row16];
#pragma unroll
    for (int s = 0; s < 4; ++s) acc[s][nt] = (f32x4){bv, bv, bv, bv};
  }
#pragma unroll
  for (int kt = 0; kt < 4; ++kt) {
#pragma unroll
    for (int nt = 0; nt < 8; ++nt) {
      bf16x8 bw = *(const bf16x8*)(pw + ((size_t)((8 + kt) * 8 + nt) * 64 + lane) * 8);
#pragma unroll
      for (int s = 0; s < 4; ++s)
        acc[s][nt] = __builtin_amdgcn_mfma_f32_16x16x32_bf16(ebf[s][kt], bw, acc[s][nt], 0, 0, 0);
    }
  }

  // ---- transpose raw (E@W0c + b0), no relu yet ----
#pragma unroll
  for (int s = 0; s < 4; ++s) stage_t<false>(hb + s * 4096, acc[s], grp, row16);
  asm volatile("s_waitcnt lgkmcnt(0)" ::: "memory");
  __builtin_amdgcn_sched_barrier(0);

  // ---- layer 1 with fused h1 = relu(staged + P[s] + Q[r]) ----
  f32x4 acc2[4][8];
#pragma unroll
  for (int nt = 0; nt < 8; ++nt) {
    float bv = b1[nt * 16 + row16];
#pragma unroll
    for (int s = 0; s < 4; ++s) acc2[s][nt] = (f32x4){bv, bv, bv, bv};
  }
  const unsigned short* w1p = pw + 49152;
#pragma unroll
  for (int kt = 0; kt < 4; ++kt) {
    bf16x8 af[4];
#pragma unroll
    for (int s = 0; s < 4; ++s) {
      const float* pp = P + (size_t)sx[s] * DF + kt * 32 + grp * 8;
      const float* qq = Q + (size_t)rx[s] * DF + kt * 32 + grp * 8;
      float4 p0 = *(const float4*)pp, p1 = *(const float4*)(pp + 4);
      float4 q0 = *(const float4*)qq, q1 = *(const float4*)(qq + 4);
      bf16x8 raw = read_a(hb + s * 4096, kt, grp, row16);
      bf16x8 h;
      h[0] = (__bf16)fmaxf((float)raw[0] + p0.x + q0.x, 0.f);
      h[1] = (__bf16)fmaxf((float)raw[1] + p0.y + q0.y, 0.f);
      h[2] = (__bf16)fmaxf((float)raw[2] + p0.z + q0.z, 0.f);
      h[3] = (__bf16)fmaxf((float)raw[3] + p0.w + q0.w, 0.f);
      h[4] = (__bf16)fmaxf((float)raw[4] + p1.x + q1.x, 0.f);
      h[5] = (__bf16)fmaxf((float)raw[5] + p1.y + q1.y, 0.f);
      h[6] = (__bf16)fmaxf((float)raw[6] + p1.z + q1.z, 0.f);
      h[7] = (__bf16)fmaxf((float)raw[7] + p1.w + q1.w, 0.f);
      af[s] = h;
    }
#pragma unroll
    for (int nt = 0; nt < 8; ++nt) {
      bf16x8 bw = *(const bf16x8*)(w1p + ((size_t)(kt * 8 + nt) * 64 + lane) * 8);
#pragma unroll
      for (int s = 0; s < 4; ++s)
        acc2[s][nt] = __builtin_amdgcn_mfma_f32_16x16x32_bf16(af[s], bw, acc2[s][nt], 0, 0, 0);
    }
  }

  // ---- epilogue: scatter-add h2 = relu(acc2) via register segmented reduction ----
#pragma unroll
  for (int s = 0; s < 4; ++s) {
    const int q = pbase + s * 16 + grp * 4;
    const int ru = rid[pbase + s * 16];                 // wave-uniform
    const bool uni = (ru == rid[pbase + s * 16 + 15]);  // whole subtile one receiver
    if (uni) {
#pragma unroll
      for (int nt = 0; nt < 8; ++nt) {
        float t = fmaxf(acc2[s][nt][0], 0.f) + fmaxf(acc2[s][nt][1], 0.f) +
                  fmaxf(acc2[s][nt][2], 0.f) + fmaxf(acc2[s][nt][3], 0.f);
        t += __shfl_xor(t, 16);
        t += __shfl_xor(t, 32);
        if (grp == 0)
          unsafeAtomicAdd(hsum + (size_t)ru * DF + nt * 16 + row16, t);
      }
    } else {
      const int ra = rid[q], rb_ = rid[q + 1], rc = rid[q + 2], rd = rid[q + 3];
#pragma unroll
      for (int nt = 0; nt < 8; ++nt) {
        const int col = nt * 16 + row16;
        float run = fmaxf(acc2[s][nt][0], 0.f);
        if (rb_ != ra) { unsafeAtomicAdd(hsum + (size_t)ra * DF + col, run); run = 0.f; }
        run += fmaxf(acc2[s][nt][1], 0.f);
        if (rc != rb_) { unsafeAtomicAdd(hsum + (size_t)rb_ * DF + col, run); run = 0.f; }
        run += fmaxf(acc2[s][nt][2], 0.f);
        if (rd != rc) { unsafeAtomicAdd(hsum + (size_t)rc * DF + col, run); run = 0.f; }
        run += fmaxf(acc2[s][nt][3], 0.f);
        unsafeAtomicAdd(hsum + (size_t)rd * DF + col, run);
      }
    }
  }
}

// ---------- kernel 4: agg = hsum@W2 + deg*b2 (hi/lo bf16), node MLP, residual, LN ----------
__global__ void __launch_bounds__(256) node_kernel(
    const float* __restrict__ nodes, const float* __restrict__ hsum,
    const int* __restrict__ deg, const float* __restrict__ b2,
    const float* __restrict__ nb0, const float* __restrict__ nb1, const float* __restrict__ nb2,
    const unsigned short* __restrict__ pw2,
    const unsigned short* __restrict__ pnw0, const unsigned short* __restrict__ pnw1,
    const unsigned short* __restrict__ pnw2, const unsigned short* __restrict__ pwn,
    const float* __restrict__ ln_s, const float* __restrict__ ln_b,
    float* __restrict__ out) {
  __shared__ char hs[16384];
  const int tid = threadIdx.x, lane = tid & 63, wave = tid >> 6;
  const int row16 = lane & 15, grp = lane >> 4;
  char* hb = hs + wave * 4096;
  const int rb = blockIdx.x * 64 + wave * 16;
  const int rA = min(rb + row16, N_NODES - 1);

  // ---- phase A: aggregated = hsum @ W2 + deg*b2 (hi/lo split for precision) ----
  f32x4 accA[8];
  {
    float d0 = (float)deg[min(rb + grp * 4 + 0, N_NODES - 1)];
    float d1 = (float)deg[min(rb + grp * 4 + 1, N_NODES - 1)];
    float d2 = (float)deg[min(rb + grp * 4 + 2, N_NODES - 1)];
    float d3 = (float)deg[min(rb + grp * 4 + 3, N_NODES - 1)];
#pragma unroll
    for (int nt = 0; nt < 8; ++nt) {
      float bc = b2[nt * 16 + row16];
      accA[nt] = (f32x4){d0 * bc, d1 * bc, d2 * bc, d3 * bc};
    }
  }
#pragma unroll
  for (int kt = 0; kt < 4; ++kt) {
    const float* hp = hsum + (size_t)rA * DF + kt * 32 + grp * 8;
    float4 h0 = *(const float4*)hp, h1v = *(const float4*)(hp + 4);
    bf16x8 hi = cvt8(h0, h1v);
    float4 l0, l1;
    l0.x = h0.x - (float)hi[0]; l0.y = h0.y - (float)hi[1];
    l0.z = h0.z - (float)hi[2]; l0.w = h0.w - (float)hi[3];
    l1.x = h1v.x - (float)hi[4]; l1.y = h1v.y - (float)hi[5];
    l1.z = h1v.z - (float)hi[6]; l1.w = h1v.w - (float)hi[7];
    bf16x8 lo = cvt8(l0, l1);
#pragma unroll
    for (int nt = 0; nt < 8; ++nt) {
      bf16x8 bw = *(const bf16x8*)(pw2 + ((size_t)(kt * 8 + nt) * 64 + lane) * 8);
      accA[nt] = __builtin_amdgcn_mfma_f32_16x16x32_bf16(hi, bw, accA[nt], 0, 0, 0);
      accA[nt] = __builtin_amdgcn_mfma_f32_16x16x32_bf16(lo, bw, accA[nt], 0, 0, 0);
    }
  }
  stage_t<false>(hb, accA, grp, row16);   // raw (aggregated can be negative)
  asm volatile("s_waitcnt lgkmcnt(0)" ::: "memory");
  __builtin_amdgcn_sched_barrier(0);

  // ---- node layer 0: K=256 = [nodes | aggregated] ----
  f32x4 acc[8];
#pragma unroll
  for (int nt = 0; nt < 8; ++nt) {
    float b = nb0[nt * 16 + row16];
    acc[nt] = (f32x4){b, b, b, b};
  }
#pragma unroll
  for (int kt = 0; kt < 8; ++kt) {
    bf16x8 af;
    if (kt < 4) {
      const float* p = nodes + (size_t)rA * DF + kt * 32 + grp * 8;
      af = cvt8(*(const float4*)p, *(const float4*)(p + 4));
    } else {
      af = read_a(hb, kt - 4, grp, row16);
    }
#pragma unroll
    for (int nt = 0; nt < 8; ++nt) {
      bf16x8 bw = *(const bf16x8*)(pnw0 + ((size_t)(kt * 8 + nt) * 64 + lane) * 8);
      acc[nt] = __builtin_amdgcn_mfma_f32_16x16x32_bf16(af, bw, acc[nt], 0, 0, 0);
    }
  }
  asm volatile("s_waitcnt lgkmcnt(0)" ::: "memory");
  __builtin_amdgcn_sched_barrier(0);
  stage_t<true>(hb, acc, grp, row16);
  asm volatile("s_waitcnt lgkmcnt(0)" ::: "memory");
  __builtin_amdgcn_sched_barrier(0);

  f32x4 acc2[8];
#pragma unroll
  for (int nt = 0; nt < 8; ++nt) {
    float b = nb1[nt * 16 + row16];
    acc2[nt] = (f32x4){b, b, b, b};
  }
#pragma unroll
  for (int kt = 0; kt < 4; ++kt) {
    bf16x8 af = read_a(hb, kt, grp, row16);
#pragma unroll
    for (int nt = 0; nt < 8; ++nt) {
      bf16x8 bw = *(const bf16x8*)(pnw1 + ((size_t)(kt * 8 + nt) * 64 + lane) * 8);
      acc2[nt] = __builtin_amdgcn_mfma_f32_16x16x32_bf16(af, bw, acc2[nt], 0, 0, 0);
    }
  }
  asm volatile("s_waitcnt lgkmcnt(0)" ::: "memory");
  __builtin_amdgcn_sched_barrier(0);
  stage_t<true>(hb, acc2, grp, row16);
  asm volatile("s_waitcnt lgkmcnt(0)" ::: "memory");
  __builtin_amdgcn_sched_barrier(0);

  f32x4 acc3[8];
#pragma unroll
  for (int nt = 0; nt < 8; ++nt) {
    float b = nb2[nt * 16 + row16];
    acc3[nt] = (f32x4){b, b, b, b};
  }
#pragma unroll
  for (int kt = 0; kt < 4; ++kt) {
    bf16x8 af = read_a(hb, kt, grp, row16);
#pragma unroll
    for (int nt = 0; nt < 8; ++nt) {
      bf16x8 bw = *(const bf16x8*)(pnw2 + ((size_t)(kt * 8 + nt) * 64 + lane) * 8);
      acc3[nt] = __builtin_amdgcn_mfma_f32_16x16x32_bf16(af, bw, acc3[nt], 0, 0, 0);
    }
  }
  f32x4 accR[8];
#pragma unroll
  for (int nt = 0; nt < 8; ++nt) accR[nt] = (f32x4){0.f, 0.f, 0.f, 0.f};
#pragma unroll
  for (int kt = 0; kt < 4; ++kt) {
    const float* p = nodes + (size_t)rA * DF + kt * 32 + grp * 8;
    bf16x8 af = cvt8(*(const float4*)p, *(const float4*)(p + 4));
#pragma unroll
    for (int nt = 0; nt < 8; ++nt) {
      bf16x8 bw = *(const bf16x8*)(pwn + ((size_t)(kt * 8 + nt) * 64 + lane) * 8);
      accR[nt] = __builtin_amdgcn_mfma_f32_16x16x32_bf16(af, bw, accR[nt], 0, 0, 0);
    }
  }

  float y[8][4];
#pragma unroll
  for (int nt = 0; nt < 8; ++nt)
#pragma unroll
    for (int i = 0; i < 4; ++i) y[nt][i] = acc3[nt][i] + accR[nt][i];

  float mean[4], rstd[4];
#pragma unroll
  for (int i = 0; i < 4; ++i) {
    float s = 0.f;
#pragma unroll
    for (int nt = 0; nt < 8; ++nt) s += y[nt][i];
    s += __shfl_xor(s, 1); s += __shfl_xor(s, 2);
    s += __shfl_xor(s, 4); s += __shfl_xor(s, 8);
    mean[i] = s * (1.0f / 128.0f);
  }
#pragma unroll
  for (int i = 0; i < 4; ++i) {
    float v = 0.f;
#pragma unroll
    for (int nt = 0; nt < 8; ++nt) {
      float d = y[nt][i] - mean[i];
      v += d * d;
    }
    v += __shfl_xor(v, 1); v += __shfl_xor(v, 2);
    v += __shfl_xor(v, 4); v += __shfl_xor(v, 8);
    rstd[i] = rsqrtf(v * (1.0f / 128.0f) + 1e-6f);
  }
#pragma unroll
  for (int nt = 0; nt < 8; ++nt) {
    const float ls = ln_s[nt * 16 + row16];
    const float lb = ln_b[nt * 16 + row16];
#pragma unroll
    for (int i = 0; i < 4; ++i) {
      const int r = rb + grp * 4 + i;
      if (r < N_NODES)
        out[(size_t)r * DF + nt * 16 + row16] = (y[nt][i] - mean[i]) * rstd[i] * ls + lb;
    }
  }
}

// ---------- launch ----------
extern "C" void kernel_launch(void* const* d_in, const int* in_sizes, int n_in,
                              void* d_out, int out_size, void* d_ws, size_t ws_size,
                              hipStream_t stream) {
  const float* nodes     = (const float*)d_in[0];
  const float* edges     = (const float*)d_in[1];
  const int*   senders   = (const int*)d_in[2];
  const int*   receivers = (const int*)d_in[3];
  const float* msg_w0 = (const float*)d_in[4];
  const float* msg_b0 = (const float*)d_in[5];
  const float* msg_w1 = (const float*)d_in[6];
  const float* msg_b1 = (const float*)d_in[7];
  const float* msg_w2 = (const float*)d_in[8];
  const float* msg_b2 = (const float*)d_in[9];
  const float* node_w0 = (const float*)d_in[10];
  const float* node_b0 = (const float*)d_in[11];
  const float* node_w1 = (const float*)d_in[12];
  const float* node_b1 = (const float*)d_in[13];
  const float* node_w2 = (const float*)d_in[14];
  const float* node_b2 = (const float*)d_in[15];
  const float* w_node   = (const float*)d_in[16];
  const float* ln_scale = (const float*)d_in[17];
  const float* ln_bias  = (const float*)d_in[18];

  char* ws = (char*)d_ws;
  float* hsum           = (float*)ws;                          // 5,120,000 B
  unsigned short* pw    = (unsigned short*)(ws + 5120000);     //   327,680 B
  unsigned short* nbf   = (unsigned short*)(ws + 5447680);     // 2,560,000 B
  int* deg              = (int*)(ws + 8007680);                //    40,000 B
  int* cursor           = (int*)(ws + 8047680);                //    40,000 B
  int* rowstart         = (int*)(ws + 8087680);                //    40,008 B
  int* eid              = (int*)(ws + 8127688);                // 2,560,000 B
  int* rid              = (int*)(ws + 10687688);               // 2,560,000 B
  int* ssend            = (int*)(ws + 13247688);               // 2,560,000 B
  float* P              = (float*)(ws + 15807744);             // 5,120,000 B (16B aligned)
  float* Q              = (float*)(ws + 20927744);             // 5,120,000 B (end ~26 MB)

  hipMemsetAsync(hsum, 0, (size_t)N_NODES * DF * sizeof(float), stream);
  hipMemsetAsync(deg, 0, 80000, stream);   // deg + cursor (adjacent)

  pack_prep<<<(163840 + N_NODES * DF) / 256, 256, 0, stream>>>(
      msg_w0, msg_w1, msg_w2, node_w0, node_w1, node_w2, w_node, nodes, pw, nbf);

  hist_kernel<<<N_EDGES / 256, 256, 0, stream>>>(receivers, deg);
  scan_kernel<<<1, 1024, 0, stream>>>(deg, rowstart);
  scatter_idx<<<N_EDGES / 256, 256, 0, stream>>>(receivers, senders, rowstart, cursor,
                                                 eid, rid, ssend);
  pq_kernel<<<157, 256, 0, stream>>>(nbf, pw, P, Q);

  msg_kernel<<<N_EDGES / 256, 256, 0, stream>>>(
      edges, eid, rid, ssend, msg_b0, msg_b1, pw, P, Q, hsum);

  node_kernel<<<157, 256, 0, stream>>>(nodes, hsum, deg, msg_b2,
                                       node_b0, node_b1, node_b2,
                                       pw + 65536,
                                       pw + 81920, pw + 114688, pw + 131072, pw + 147456,
                                       ln_scale, ln_bias, (float*)d_out);
}